// Round 17
// baseline (206.750 us; speedup 1.0000x reference)
//
#include <hip/hip_runtime.h>
#include <hip/hip_bf16.h>

#define N_SAMPLES 128
#define LAST_DIST 1e10f
#define EPS 1e-10f

// DPP ctrl encodings (gfx9/CDNA lineage, valid on gfx950)
#define DPP_ROW_SHR(n)   (0x110 | (n))   // lane i <- lane i-n (within 16-lane row)
#define DPP_WAVE_SHL1    0x130           // lane i <- lane i+1 (whole wave)
#define DPP_WAVE_SHR1    0x138           // lane i <- lane i-1 (whole wave)
#define DPP_ROW_BCAST15  0x142           // lane15 -> lanes16..31, lane47 -> 48..63
#define DPP_ROW_BCAST31  0x143           // lane31 -> lanes32..63

template <int Ctrl, int RowMask = 0xf, int BankMask = 0xf>
__device__ __forceinline__ float dpp_mov(float oldv, float src) {
    return __int_as_float(__builtin_amdgcn_update_dpp(
        __float_as_int(oldv), __float_as_int(src), Ctrl, RowMask, BankMask, false));
}

__device__ __forceinline__ float readlane_f(float v, int lane) {
    return __int_as_float(__builtin_amdgcn_readlane(__float_as_int(v), lane));
}

// two independent 64-lane inclusive prefix products, lockstep-interleaved
__device__ __forceinline__ void wave_iprod2(float& p0, float& p1) {
    p0 *= dpp_mov<DPP_ROW_SHR(1)>(1.0f, p0);  p1 *= dpp_mov<DPP_ROW_SHR(1)>(1.0f, p1);
    p0 *= dpp_mov<DPP_ROW_SHR(2)>(1.0f, p0);  p1 *= dpp_mov<DPP_ROW_SHR(2)>(1.0f, p1);
    p0 *= dpp_mov<DPP_ROW_SHR(4)>(1.0f, p0);  p1 *= dpp_mov<DPP_ROW_SHR(4)>(1.0f, p1);
    p0 *= dpp_mov<DPP_ROW_SHR(8)>(1.0f, p0);  p1 *= dpp_mov<DPP_ROW_SHR(8)>(1.0f, p1);
    p0 *= dpp_mov<DPP_ROW_BCAST15, 0xa>(1.0f, p0);
    p1 *= dpp_mov<DPP_ROW_BCAST15, 0xa>(1.0f, p1);
    p0 *= dpp_mov<DPP_ROW_BCAST31, 0xc>(1.0f, p0);
    p1 *= dpp_mov<DPP_ROW_BCAST31, 0xc>(1.0f, p1);
}

// 64-lane sum; result valid in lane 63
__device__ __forceinline__ float wave_sum63(float v) {
    v += dpp_mov<DPP_ROW_SHR(1)>(0.0f, v);
    v += dpp_mov<DPP_ROW_SHR(2)>(0.0f, v);
    v += dpp_mov<DPP_ROW_SHR(4)>(0.0f, v);
    v += dpp_mov<DPP_ROW_SHR(8)>(0.0f, v);
    v += dpp_mov<DPP_ROW_BCAST15, 0xa>(0.0f, v);
    v += dpp_mov<DPP_ROW_BCAST31, 0xc>(0.0f, v);
    return v;
}

__device__ __forceinline__ float fast_sigmoid(float x) {
    return __builtin_amdgcn_rcpf(1.0f + __expf(-x));
}

// One wave per TWO rays; lane l owns samples (l, 64+l) of each ray.
// Dense unit-stride loads; all cross-lane ops are DPP (VALU pipe);
// two independent scan chains give 2-way ILP through every dep chain.
__global__ __launch_bounds__(256, 4) void render_rays_kernel(
    const float4* __restrict__ raw,   // [R*S] float4 (rgb + sigma)
    const float*  __restrict__ zv,    // [R*S] z_vals
    float* __restrict__ out,          // [R*3]
    int n_rays)
{
    const int wave = threadIdx.x >> 6;
    const int lane = threadIdx.x & 63;
    const int r0 = (blockIdx.x * (blockDim.x >> 6) + wave) * 2;
    if (r0 >= n_rays) return;
    const int r1 = r0 + 1;

    const size_t b0 = (size_t)r0 * N_SAMPLES;
    const size_t b1 = (size_t)r1 * N_SAMPLES;

    // ---- dense loads: 80 B/lane in flight ----
    const float4 fa0 = raw[b0 + lane];
    const float4 fb0 = raw[b0 + 64 + lane];
    const float4 fa1 = raw[b1 + lane];
    const float4 fb1 = raw[b1 + 64 + lane];
    const float  za0 = zv[b0 + lane];
    const float  zb0 = zv[b0 + 64 + lane];
    const float  za1 = zv[b1 + lane];
    const float  zb1 = zv[b1 + 64 + lane];

    // ---- dists via wave_shl1 ----
    const float za0n = dpp_mov<DPP_WAVE_SHL1>(0.0f, za0);
    const float zb0n = dpp_mov<DPP_WAVE_SHL1>(0.0f, zb0);
    const float za1n = dpp_mov<DPP_WAVE_SHL1>(0.0f, za1);
    const float zb1n = dpp_mov<DPP_WAVE_SHL1>(0.0f, zb1);
    const float z64_0 = readlane_f(zb0, 0);
    const float z64_1 = readlane_f(zb1, 0);
    const float da0 = ((lane == 63) ? z64_0 : za0n) - za0;
    const float db0 = (lane == 63) ? LAST_DIST : (zb0n - zb0);
    const float da1 = ((lane == 63) ? z64_1 : za1n) - za1;
    const float db1 = (lane == 63) ? LAST_DIST : (zb1n - zb1);

    // ---- survival t = exp(-relu(sigma)*d) + eps ----
    const float ea0 = __expf(-fmaxf(fa0.w, 0.0f) * da0);
    const float eb0 = __expf(-fmaxf(fb0.w, 0.0f) * db0);
    const float ea1 = __expf(-fmaxf(fa1.w, 0.0f) * da1);
    const float eb1 = __expf(-fmaxf(fb1.w, 0.0f) * db1);

    // ---- first-half scans (both rays interleaved) ----
    float Pa0 = ea0 + EPS, Pa1 = ea1 + EPS;
    wave_iprod2(Pa0, Pa1);
    float Ta0 = dpp_mov<DPP_WAVE_SHR1>(1.0f, Pa0);   // exclusive; lane0 -> 1
    float Ta1 = dpp_mov<DPP_WAVE_SHR1>(1.0f, Pa1);
    const float totA0 = readlane_f(Pa0, 63);
    const float totA1 = readlane_f(Pa1, 63);

    // ---- second-half scans ----
    float Pb0 = eb0 + EPS, Pb1 = eb1 + EPS;
    wave_iprod2(Pb0, Pb1);
    float Tb0 = dpp_mov<DPP_WAVE_SHR1>(1.0f, Pb0) * totA0;
    float Tb1 = dpp_mov<DPP_WAVE_SHR1>(1.0f, Pb1) * totA1;

    // ---- weights & weighted colors ----
    const float wa0 = (1.0f - ea0) * Ta0;
    const float wb0 = (1.0f - eb0) * Tb0;
    const float wa1 = (1.0f - ea1) * Ta1;
    const float wb1 = (1.0f - eb1) * Tb1;

    float x0 = wa0 * fast_sigmoid(fa0.x) + wb0 * fast_sigmoid(fb0.x);
    float y0 = wa0 * fast_sigmoid(fa0.y) + wb0 * fast_sigmoid(fb0.y);
    float z0 = wa0 * fast_sigmoid(fa0.z) + wb0 * fast_sigmoid(fb0.z);
    float x1 = wa1 * fast_sigmoid(fa1.x) + wb1 * fast_sigmoid(fb1.x);
    float y1 = wa1 * fast_sigmoid(fa1.y) + wb1 * fast_sigmoid(fb1.y);
    float z1 = wa1 * fast_sigmoid(fa1.z) + wb1 * fast_sigmoid(fb1.z);

    // ---- reductions (6 independent chains; totals in lane 63) ----
    x0 = wave_sum63(x0); y0 = wave_sum63(y0); z0 = wave_sum63(z0);
    x1 = wave_sum63(x1); y1 = wave_sum63(y1); z1 = wave_sum63(z1);

    if (lane == 63) {
        const size_t o = (size_t)r0 * 3;      // 6 contiguous floats
        out[o + 0] = x0; out[o + 1] = y0; out[o + 2] = z0;
        out[o + 3] = x1; out[o + 4] = y1; out[o + 5] = z1;
    }
}

extern "C" void kernel_launch(void* const* d_in, const int* in_sizes, int n_in,
                              void* d_out, int out_size, void* d_ws, size_t ws_size,
                              hipStream_t stream) {
    const float4* raw = (const float4*)d_in[0];   // [R, S, 4] f32
    const float*  zv  = (const float*)d_in[1];    // [R, S]   f32
    float* out        = (float*)d_out;            // [R, 3]   f32

    const int n_rays = in_sizes[0] / (N_SAMPLES * 4);

    const int waves_per_block = 4;                // 256 threads
    const int block = waves_per_block * 64;
    const int rays_per_block = waves_per_block * 2;
    const int grid = (n_rays + rays_per_block - 1) / rays_per_block;

    render_rays_kernel<<<grid, block, 0, stream>>>(raw, zv, out, n_rays);
}